// Round 3
// baseline (712.439 us; speedup 1.0000x reference)
//
#include <hip/hip_runtime.h>
#include <stdint.h>

// ============================================================================
// CPC forward on MI355X (gfx950).
// Pipeline: k_prep (f16 weight convert + transpose, zero accumulators)
//   -> k_gemm64<256,f32A,relu>  h1 = relu(rr @ w1 + b1)            [MFMA f16]
//   -> k_enc2                   z  = l2norm(h1 @ w2 + b2)          [MFMA f16]
//   -> k_gemm64<128,f16A,->     gx = z @ W_ih^T + b_ih             [MFMA f16]
//   -> k_gru                    sequential scan, W_hh in VGPRs, v_dot2_f32_f16
//   -> k_cpc                    fused preds->l2norm->logits->online LSE/acc
//   -> k_fin                    scalar finalize
// Precision: f16 storage/operands, f32 accumulation everywhere.
// R2: k_gru was L2-BW-bound (compiler rematerialized W_hh loads every step:
// VGPR_Count=84 < 128 needed; 12.9GB/328us = 39TB/s = L2 ceiling). New scheme:
// one ds_read_b64/wave/step + v_readlane h-pairs into SGPRs feeding fdot2's
// SGPR operand slot -> W stays VGPR-resident (~150 regs), LDS pipe ~idle,
// bottleneck moves to per-SIMD VALU issue (~1650 cyc/step vs 3072).
// ============================================================================

typedef _Float16 f16;
typedef __attribute__((ext_vector_type(2))) _Float16 f16x2;
typedef __attribute__((ext_vector_type(8))) _Float16 f16x8;
typedef __attribute__((ext_vector_type(4))) float f32x4;

__device__ __forceinline__ f16x2 u2h(unsigned int x) { return __builtin_bit_cast(f16x2, x); }
__device__ __forceinline__ float sigm_(float x) { return __builtin_amdgcn_rcpf(1.f + __expf(-x)); }
__device__ __forceinline__ float tanh_(float x) { return 1.f - 2.f * __builtin_amdgcn_rcpf(__expf(2.f * x) + 1.f); }

#define NTOT_LOSS 374784.0f  // 12 * 128 * 244

// ---------------------------------------------------------------------------
// K0: convert weights to f16 (transposing where the GEMMs want [N][K]),
//     zero the loss/accuracy accumulators.
// ---------------------------------------------------------------------------
__global__ void k_prep(const float* __restrict__ w1, const float* __restrict__ w2,
                       const float* __restrict__ wih, const float* __restrict__ whh,
                       const float* __restrict__ wkw,
                       f16* __restrict__ w1T, f16* __restrict__ w2T, f16* __restrict__ wihF,
                       f16* __restrict__ whhF, f16* __restrict__ wkT, float* __restrict__ accb) {
  const int stride = gridDim.x * blockDim.x;
  const int tid = blockIdx.x * blockDim.x + threadIdx.x;
  if (tid == 0) { accb[0] = 0.f; accb[1] = 0.f; }
  // w1 (256k x 256n) -> w1T[n][k]
  for (int i = tid; i < 65536; i += stride) { int n = i >> 8, k = i & 255; w1T[i] = (f16)w1[k * 256 + n]; }
  // w2 (256k x 128n) -> w2T[n][k]  (n<128, k<256)
  for (int i = tid; i < 32768; i += stride) { int n = i >> 8, k = i & 255; w2T[i] = (f16)w2[k * 128 + n]; }
  // W_ih (768 x 128) already [N][K] for gx GEMM
  for (int i = tid; i < 98304; i += stride) wihF[i] = (f16)wih[i];
  // W_hh (768 x 256) row-major, consumed row-per-thread in k_gru
  for (int i = tid; i < 196608; i += stride) whhF[i] = (f16)whh[i];
  // Wk_w (12,256c,128d) -> wkT[kk][d][c]
  for (int i = tid; i < 393216; i += stride) {
    int kk = i >> 15, rem = i & 32767, d = rem >> 8, c = rem & 255;
    wkT[i] = (f16)wkw[(kk << 15) + c * 128 + d];
  }
}

// ---------------------------------------------------------------------------
// Generic 64x64-tile f16 MFMA GEMM: out[m][n] = act(A[m][:] . BT[n][:] + bias[n])
// A: [M][KTOT] (f32 or f16), BT: [N][KTOT] f16.  4 waves, wave = 16 rows x 64 cols.
// ---------------------------------------------------------------------------
template <int KTOT, bool AF32, bool RELU>
__global__ __launch_bounds__(256) void k_gemm64(const void* __restrict__ Aptr,
                                                const f16* __restrict__ BT,
                                                const float* __restrict__ bias,
                                                f16* __restrict__ out, const int NT) {
  __shared__ __align__(16) f16 Al[64][40];  // +8 pad: kills ds_read bank conflicts
  __shared__ __align__(16) f16 Bl[64][40];
  const int m0 = blockIdx.x * 64;
  const int n0 = blockIdx.y * 64;
  const int t = threadIdx.x;
  const int w = t >> 6, l = t & 63, lr = l & 15, lg = l >> 4;
  const int arow = t >> 2, akq = (t & 3) * 8;
  f32x4 acc[4] = {};
  for (int ks = 0; ks < KTOT / 32; ++ks) {
    const int kc = ks * 32;
    __syncthreads();
    if constexpr (AF32) {
      const float* src = (const float*)Aptr + (size_t)(m0 + arow) * KTOT + kc + akq;
      float4 v0 = *(const float4*)src;
      float4 v1 = *(const float4*)(src + 4);
      f16x8 hv = {(f16)v0.x, (f16)v0.y, (f16)v0.z, (f16)v0.w,
                  (f16)v1.x, (f16)v1.y, (f16)v1.z, (f16)v1.w};
      *(f16x8*)&Al[arow][akq] = hv;
    } else {
      const f16* src = (const f16*)Aptr + (size_t)(m0 + arow) * KTOT + kc + akq;
      *(f16x8*)&Al[arow][akq] = *(const f16x8*)src;
    }
    *(f16x8*)&Bl[arow][akq] = *(const f16x8*)(BT + (size_t)(n0 + arow) * KTOT + kc + akq);
    __syncthreads();
    // A-frag: row = lane&15, k = 8*(lane>>4)+j ; B-frag: col = lane&15, same k
    f16x8 af = *(const f16x8*)&Al[16 * w + lr][lg * 8];
#pragma unroll
    for (int nt = 0; nt < 4; ++nt) {
      f16x8 bf = *(const f16x8*)&Bl[nt * 16 + lr][lg * 8];
      acc[nt] = __builtin_amdgcn_mfma_f32_16x16x32_f16(af, bf, acc[nt], 0, 0, 0);
    }
  }
  // C/D: col = lane&15, row = 4*(lane>>4)+r   [m89-verified layout]
#pragma unroll
  for (int nt = 0; nt < 4; ++nt) {
    const int n = n0 + nt * 16 + lr;
    const float bb = bias[n];
#pragma unroll
    for (int r = 0; r < 4; ++r) {
      const int m = m0 + 16 * w + lg * 4 + r;
      float v = acc[nt][r] + bb;
      if (RELU) v = fmaxf(v, 0.f);
      out[(size_t)m * NT + n] = (f16)v;
    }
  }
}

// ---------------------------------------------------------------------------
// K2: z = l2norm(h1 @ w2T + b2). N=128 so each wave owns full rows -> in-wave
// shfl row-norm. Writes z f32 (output) + z f16 (workspace).
// ---------------------------------------------------------------------------
__global__ __launch_bounds__(256) void k_enc2(const f16* __restrict__ A, const f16* __restrict__ BT,
                                              const float* __restrict__ bias,
                                              float* __restrict__ zf32, f16* __restrict__ zf16) {
  __shared__ __align__(16) f16 Al[64][40];
  __shared__ __align__(16) f16 Bl[128][40];
  const int m0 = blockIdx.x * 64;
  const int t = threadIdx.x;
  const int w = t >> 6, l = t & 63, lr = l & 15, lg = l >> 4;
  const int arow = t >> 2, akq = (t & 3) * 8;
  f32x4 acc[8] = {};
  for (int ks = 0; ks < 8; ++ks) {
    const int kc = ks * 32;
    __syncthreads();
    *(f16x8*)&Al[arow][akq] = *(const f16x8*)(A + (size_t)(m0 + arow) * 256 + kc + akq);
#pragma unroll
    for (int hh = 0; hh < 2; ++hh) {
      const int brow = arow + 64 * hh;
      *(f16x8*)&Bl[brow][akq] = *(const f16x8*)(BT + (size_t)brow * 256 + kc + akq);
    }
    __syncthreads();
    f16x8 af = *(const f16x8*)&Al[16 * w + lr][lg * 8];
#pragma unroll
    for (int nt = 0; nt < 8; ++nt) {
      f16x8 bf = *(const f16x8*)&Bl[nt * 16 + lr][lg * 8];
      acc[nt] = __builtin_amdgcn_mfma_f32_16x16x32_f16(af, bf, acc[nt], 0, 0, 0);
    }
  }
  float v[8][4];
#pragma unroll
  for (int nt = 0; nt < 8; ++nt) {
    const float bb = bias[nt * 16 + lr];
#pragma unroll
    for (int r = 0; r < 4; ++r) v[nt][r] = acc[nt][r] + bb;
  }
#pragma unroll
  for (int r = 0; r < 4; ++r) {
    float ss = 0.f;
#pragma unroll
    for (int nt = 0; nt < 8; ++nt) ss += v[nt][r] * v[nt][r];
    ss += __shfl_xor(ss, 1); ss += __shfl_xor(ss, 2); ss += __shfl_xor(ss, 4); ss += __shfl_xor(ss, 8);
    const float scl = 1.f / fmaxf(sqrtf(ss), 1e-12f);
    const int m = m0 + 16 * w + lg * 4 + r;
#pragma unroll
    for (int nt = 0; nt < 8; ++nt) {
      const int n = nt * 16 + lr;
      const float z = v[nt][r] * scl;
      zf32[(size_t)m * 128 + n] = z;
      zf16[(size_t)m * 128 + n] = (f16)z;
    }
  }
}

// ---------------------------------------------------------------------------
// K4: GRU scan. 128 blocks (one batch row each) x 768 threads.
// Thread o: gate g = o>>8 (0=r,1=z,2=n), column c = o&255.
// W_hh row (256 f16 = 32 uint4 = 128 VGPR) resident; h broadcast:
//   lane i ds_read_b64's h[4i..4i+3] (1 LDS instr/wave/step), then
//   v_readlane pulls each h-pair into an SGPR feeding fdot2's SGPR slot.
// h-pair p (h[2p],h[2p+1]) lives in lane p>>1, component p&1.
// ---------------------------------------------------------------------------
__global__ __launch_bounds__(768, 3) void k_gru(const f16* __restrict__ gx, const f16* __restrict__ whh,
                                                const float* __restrict__ bhh,
                                                float* __restrict__ cout, f16* __restrict__ cf16) {
  __shared__ __align__(16) f16 h_lds[2][256];
  __shared__ float rz[2][256];
  const int b = blockIdx.x;
  const int o = threadIdx.x;
  const int g = o >> 8;
  const int c = o & 255;
  const int lane = o & 63;
  uint4 wv[32];
  {
    const uint4* wp = (const uint4*)(whh + (size_t)o * 256);
#pragma unroll
    for (int i = 0; i < 32; ++i) wv[i] = wp[i];
  }
  const float bh = bhh[o];
  if (o < 256) h_lds[0][o] = (f16)0.f;
  float h_own = 0.f;
  const f16* gxp = gx + (size_t)b * 256 * 768 + o;
  float* coutp = cout + (size_t)b * 256 * 256 + c;
  f16* cfp = cf16 + (size_t)b * 256 * 256 + c;
  __syncthreads();
#pragma unroll 1
  for (int tt = 0; tt < 256; ++tt) {
    const int cur = tt & 1;
    const float gxv = (float)gxp[tt * 768];
    // one LDS read per lane: h[4*lane .. 4*lane+3]
    const uint2 hreg = *(const uint2*)&h_lds[cur][lane * 4];
    float a0 = 0.f, a1 = 0.f, a2 = 0.f, a3 = 0.f;
#pragma unroll
    for (int j = 0; j < 32; ++j) {
      // wv[j] covers h-pairs 4j..4j+3 -> lanes 2j (x,y comps) and 2j+1 (x,y)
      const unsigned p0 = __builtin_amdgcn_readlane(hreg.x, 2 * j);
      const unsigned p1 = __builtin_amdgcn_readlane(hreg.y, 2 * j);
      const unsigned p2 = __builtin_amdgcn_readlane(hreg.x, 2 * j + 1);
      const unsigned p3 = __builtin_amdgcn_readlane(hreg.y, 2 * j + 1);
      a0 = __builtin_amdgcn_fdot2(u2h(wv[j].x), u2h(p0), a0, false);
      a1 = __builtin_amdgcn_fdot2(u2h(wv[j].y), u2h(p1), a1, false);
      a2 = __builtin_amdgcn_fdot2(u2h(wv[j].z), u2h(p2), a2, false);
      a3 = __builtin_amdgcn_fdot2(u2h(wv[j].w), u2h(p3), a3, false);
    }
    const float dot = (a0 + a1) + (a2 + a3) + bh;  // includes b_hh
    if (g < 2) rz[g][c] = sigm_(gxv + dot);
    __syncthreads();
    if (g == 2) {
      const float r = rz[0][c], zz = rz[1][c];
      const float n = tanh_(gxv + r * dot);
      const float hn = (1.f - zz) * n + zz * h_own;
      h_own = hn;
      h_lds[cur ^ 1][c] = (f16)hn;
      coutp[tt * 256] = hn;
      cfp[tt * 256] = (f16)hn;
    }
    __syncthreads();
  }
}

// ---------------------------------------------------------------------------
// K5: fused preds -> l2norm -> logits -> online LSE / pos / neg-max -> loss&acc.
// grid (tchunk=4, b=128, k=12), 256 threads. Never materializes logits.
// ---------------------------------------------------------------------------
__global__ __launch_bounds__(256) void k_cpc(const f16* __restrict__ cf16, const f16* __restrict__ zf16,
                                             const f16* __restrict__ wkT, const float* __restrict__ wkb,
                                             float* __restrict__ accb) {
  __shared__ __align__(16) f16 SMc[64 * 264];   // c-tile [64][264], reused as z-chunk [64][136]
  __shared__ __align__(16) f16 Bl[128][40];
  __shared__ __align__(16) f16 P[64][136];
  __shared__ float red[2];
  const int tc = blockIdx.x, b = blockIdx.y, kk = blockIdx.z;
  const int t0 = tc * 64;
  const int t = threadIdx.x;
  const int w = t >> 6, l = t & 63, lr = l & 15, lg = l >> 4;
  // ---- stage c tile (64 t-rows x 256 c = 8192 u32, 32 iters of 256) ----
  {
    const uint32_t* src = (const uint32_t*)(cf16 + ((size_t)b * 256 + t0) * 256);
    uint32_t* dst = (uint32_t*)SMc;
#pragma unroll
    for (int it = 0; it < 32; ++it) {
      const int idx = it * 256 + t, row = idx >> 7, cw = idx & 127;
      dst[row * 132 + cw] = src[row * 128 + cw];
    }
  }
  // ---- preds GEMM: (64 x 128) = c(64x256) @ WkT^T, K=256 ----
  f32x4 acc[8] = {};
  for (int ks = 0; ks < 8; ++ks) {
    __syncthreads();
    {
      const uint32_t* bsrc = (const uint32_t*)(wkT + ((size_t)kk << 15));
      uint32_t* bd = (uint32_t*)Bl;
#pragma unroll
      for (int it = 0; it < 8; ++it) {
        const int idx = it * 256 + t, row = idx >> 4, kw = idx & 15;
        bd[row * 20 + kw] = bsrc[row * 128 + ks * 16 + kw];
      }
    }
    __syncthreads();
    f16x8 af = *(const f16x8*)&SMc[(16 * w + lr) * 264 + ks * 32 + lg * 8];
#pragma unroll
    for (int nt = 0; nt < 8; ++nt) {
      f16x8 bf = *(const f16x8*)&Bl[nt * 16 + lr][lg * 8];
      acc[nt] = __builtin_amdgcn_mfma_f32_16x16x32_f16(af, bf, acc[nt], 0, 0, 0);
    }
  }
  // ---- preds epilogue: bias + row l2norm -> P (f16) ----
  {
    float v[8][4];
#pragma unroll
    for (int nt = 0; nt < 8; ++nt) {
      const float bb = wkb[kk * 128 + nt * 16 + lr];
#pragma unroll
      for (int r = 0; r < 4; ++r) v[nt][r] = acc[nt][r] + bb;
    }
#pragma unroll
    for (int r = 0; r < 4; ++r) {
      float ss = 0.f;
#pragma unroll
      for (int nt = 0; nt < 8; ++nt) ss += v[nt][r] * v[nt][r];
      ss += __shfl_xor(ss, 1); ss += __shfl_xor(ss, 2); ss += __shfl_xor(ss, 4); ss += __shfl_xor(ss, 8);
      const float scl = 1.f / fmaxf(sqrtf(ss), 1e-12f);
#pragma unroll
      for (int nt = 0; nt < 8; ++nt)
        P[16 * w + lg * 4 + r][nt * 16 + lr] = (f16)(v[nt][r] * scl);
    }
  }
  __syncthreads();
  // ---- logits + online LSE/pos/negmax over 4 s-chunks of 64 ----
  float m_run[4], s_run[4], pos_v[4], neg_m[4];
#pragma unroll
  for (int r = 0; r < 4; ++r) { m_run[r] = -1e30f; s_run[r] = 0.f; pos_v[r] = -1e30f; neg_m[r] = -1e30f; }
  for (int sc = 0; sc < 4; ++sc) {
    __syncthreads();
    {
      const uint32_t* zsrc = (const uint32_t*)(zf16 + ((size_t)b * 256 + sc * 64) * 128);
      uint32_t* zd = (uint32_t*)SMc;
#pragma unroll
      for (int it = 0; it < 16; ++it) {
        const int idx = it * 256 + t, row = idx >> 6, cw = idx & 63;
        zd[row * 68 + cw] = zsrc[row * 64 + cw];
      }
    }
    __syncthreads();
    f32x4 sa[4] = {};
#pragma unroll
    for (int ks = 0; ks < 4; ++ks) {
      f16x8 af = *(const f16x8*)&P[16 * w + lr][ks * 32 + lg * 8];
#pragma unroll
      for (int nt = 0; nt < 4; ++nt) {
        f16x8 bf = *(const f16x8*)&SMc[(nt * 16 + lr) * 136 + ks * 32 + lg * 8];
        sa[nt] = __builtin_amdgcn_mfma_f32_16x16x32_f16(af, bf, sa[nt], 0, 0, 0);
      }
    }
#pragma unroll
    for (int r = 0; r < 4; ++r) {
      const int trow = t0 + 16 * w + lg * 4 + r;
      const int pos_s = trow + kk + 1;
      float vv[4];
#pragma unroll
      for (int nt = 0; nt < 4; ++nt) vv[nt] = sa[nt][r] * 10.f;  // 1/TEMP
      float cm = fmaxf(fmaxf(vv[0], vv[1]), fmaxf(vv[2], vv[3]));
      cm = fmaxf(cm, __shfl_xor(cm, 1)); cm = fmaxf(cm, __shfl_xor(cm, 2));
      cm = fmaxf(cm, __shfl_xor(cm, 4)); cm = fmaxf(cm, __shfl_xor(cm, 8));
      const float nm = fmaxf(m_run[r], cm);
      float ps = __expf(vv[0] - nm) + __expf(vv[1] - nm) + __expf(vv[2] - nm) + __expf(vv[3] - nm);
      ps += __shfl_xor(ps, 1); ps += __shfl_xor(ps, 2); ps += __shfl_xor(ps, 4); ps += __shfl_xor(ps, 8);
      s_run[r] = s_run[r] * __expf(m_run[r] - nm) + ps;
      m_run[r] = nm;
      const int sbase = sc * 64 + lr;
#pragma unroll
      for (int nt = 0; nt < 4; ++nt) {
        const int s = sbase + nt * 16;
        if (s == pos_s) pos_v[r] = vv[nt];
        else neg_m[r] = fmaxf(neg_m[r], vv[nt]);
      }
    }
  }
  // ---- finalize ----
  __syncthreads();
  if (t == 0) { red[0] = 0.f; red[1] = 0.f; }
  __syncthreads();
  float lsum = 0.f, csum = 0.f;
#pragma unroll
  for (int r = 0; r < 4; ++r) {
    float pv = pos_v[r], ng = neg_m[r];
    pv = fmaxf(pv, __shfl_xor(pv, 1)); pv = fmaxf(pv, __shfl_xor(pv, 2));
    pv = fmaxf(pv, __shfl_xor(pv, 4)); pv = fmaxf(pv, __shfl_xor(pv, 8));
    ng = fmaxf(ng, __shfl_xor(ng, 1)); ng = fmaxf(ng, __shfl_xor(ng, 2));
    ng = fmaxf(ng, __shfl_xor(ng, 4)); ng = fmaxf(ng, __shfl_xor(ng, 8));
    const int trow = t0 + 16 * w + lg * 4 + r;
    if (lr == 0 && trow < 244) {
      const float lse = m_run[r] + __logf(s_run[r]);
      lsum += lse - pv;
      csum += (pv >= ng) ? 1.f : 0.f;
    }
  }
  if (lr == 0) { atomicAdd(&red[0], lsum); atomicAdd(&red[1], csum); }
  __syncthreads();
  if (t == 0) { atomicAdd(&accb[0], red[0]); atomicAdd(&accb[1], red[1]); }
}

__global__ void k_fin(const float* __restrict__ accb, float* __restrict__ out) {
  out[0] = accb[0] * (1.0f / NTOT_LOSS);
  out[1] = accb[1] * (100.0f / NTOT_LOSS);
}

// ---------------------------------------------------------------------------
extern "C" void kernel_launch(void* const* d_in, const int* in_sizes, int n_in,
                              void* d_out, int out_size, void* d_ws, size_t ws_size,
                              hipStream_t stream) {
  (void)in_sizes; (void)n_in; (void)out_size; (void)ws_size;
  const float* rr  = (const float*)d_in[0];
  const float* w1  = (const float*)d_in[1];
  const float* b1  = (const float*)d_in[2];
  const float* w2  = (const float*)d_in[3];
  const float* b2  = (const float*)d_in[4];
  const float* wih = (const float*)d_in[5];
  const float* whh = (const float*)d_in[6];
  const float* bih = (const float*)d_in[7];
  const float* bhh = (const float*)d_in[8];
  const float* wkw = (const float*)d_in[9];
  const float* wkb = (const float*)d_in[10];
  float* out = (float*)d_out;
  char* ws = (char*)d_ws;

  // workspace layout (77.1 MB total)
  const size_t GX_B = (size_t)32768 * 768 * 2;  // 50,331,648
  f16* gx   = (f16*)ws;
  f16* h1   = (f16*)ws;  // alias: h1 (16.8MB) dead before gx is written
  f16* zf16 = (f16*)(ws + GX_B);
  f16* cf16 = (f16*)(ws + GX_B + 8388608);
  f16* w1T  = (f16*)(ws + GX_B + 8388608 + 16777216);
  f16* w2T  = w1T + 65536;
  f16* wihF = w2T + 32768;
  f16* whhF = wihF + 98304;
  f16* wkT  = whhF + 196608;
  float* accb = (float*)(wkT + 393216);

  float* zf32 = out + 2;
  float* cf32 = out + 2 + 4194304;

  k_prep<<<256, 256, 0, stream>>>(w1, w2, wih, whh, wkw, w1T, w2T, wihF, whhF, wkT, accb);
  k_gemm64<256, true, true><<<dim3(512, 4), 256, 0, stream>>>(rr, w1T, b1, h1, 256);
  k_enc2<<<dim3(512), 256, 0, stream>>>(h1, w2T, b2, zf32, zf16);
  k_gemm64<128, false, false><<<dim3(512, 12), 256, 0, stream>>>(zf16, wihF, bih, gx, 768);
  k_gru<<<128, 768, 0, stream>>>(gx, whhF, bhh, cf32, cf16);
  k_cpc<<<dim3(4, 128, 12), 256, 0, stream>>>(cf16, zf16, wkT, wkb, accb);
  k_fin<<<1, 1, 0, stream>>>(accb, out);
}

// Round 4
// 656.806 us; speedup vs baseline: 1.0847x; 1.0847x over previous
//
#include <hip/hip_runtime.h>
#include <stdint.h>

// ============================================================================
// CPC forward on MI355X (gfx950).
// Pipeline: k_prep (f16 weight convert + transpose, zero accumulators)
//   -> k_gemm64<256,f32A,relu>  h1 = relu(rr @ w1 + b1)            [MFMA f16]
//   -> k_enc2                   z  = l2norm(h1 @ w2 + b2)          [MFMA f16]
//   -> k_gemm64<128,f16A,->     gx = z @ W_ih^T + b_ih             [MFMA f16]
//   -> k_gru                    sequential scan, W_hh pinned in VGPRs
//   -> k_cpc                    fused preds->l2norm->logits->online LSE/acc
//   -> k_fin                    scalar finalize
// Precision: f16 storage/operands, f32 accumulation everywhere.
// R2/R3 lesson: compiler rematerialized the 32x global_load_dwordx4 of W_hh
// inside the timestep loop (VGPR_Count 84/76 < the 128 regs W needs) ->
// L2-latency-bound at ~3072 cyc/step. R4: pin wv[32] live via empty asm
// "+v" barriers (remat becomes illegal), revert h-broadcast to wave-uniform
// ds_read_b128 (1:4 LDS:fdot2). Expected floor ~768-1500 cyc/step.
// ============================================================================

typedef _Float16 f16;
typedef __attribute__((ext_vector_type(2))) _Float16 f16x2;
typedef __attribute__((ext_vector_type(8))) _Float16 f16x8;
typedef __attribute__((ext_vector_type(4))) float f32x4;

__device__ __forceinline__ f16x2 u2h(unsigned int x) { return __builtin_bit_cast(f16x2, x); }
__device__ __forceinline__ float sigm_(float x) { return __builtin_amdgcn_rcpf(1.f + __expf(-x)); }
__device__ __forceinline__ float tanh_(float x) { return 1.f - 2.f * __builtin_amdgcn_rcpf(__expf(2.f * x) + 1.f); }

#define NTOT_LOSS 374784.0f  // 12 * 128 * 244

// ---------------------------------------------------------------------------
// K0: convert weights to f16 (transposing where the GEMMs want [N][K]),
//     zero the loss/accuracy accumulators.
// ---------------------------------------------------------------------------
__global__ void k_prep(const float* __restrict__ w1, const float* __restrict__ w2,
                       const float* __restrict__ wih, const float* __restrict__ whh,
                       const float* __restrict__ wkw,
                       f16* __restrict__ w1T, f16* __restrict__ w2T, f16* __restrict__ wihF,
                       f16* __restrict__ whhF, f16* __restrict__ wkT, float* __restrict__ accb) {
  const int stride = gridDim.x * blockDim.x;
  const int tid = blockIdx.x * blockDim.x + threadIdx.x;
  if (tid == 0) { accb[0] = 0.f; accb[1] = 0.f; }
  // w1 (256k x 256n) -> w1T[n][k]
  for (int i = tid; i < 65536; i += stride) { int n = i >> 8, k = i & 255; w1T[i] = (f16)w1[k * 256 + n]; }
  // w2 (256k x 128n) -> w2T[n][k]  (n<128, k<256)
  for (int i = tid; i < 32768; i += stride) { int n = i >> 8, k = i & 255; w2T[i] = (f16)w2[k * 128 + n]; }
  // W_ih (768 x 128) already [N][K] for gx GEMM
  for (int i = tid; i < 98304; i += stride) wihF[i] = (f16)wih[i];
  // W_hh (768 x 256) row-major, consumed row-per-thread in k_gru
  for (int i = tid; i < 196608; i += stride) whhF[i] = (f16)whh[i];
  // Wk_w (12,256c,128d) -> wkT[kk][d][c]
  for (int i = tid; i < 393216; i += stride) {
    int kk = i >> 15, rem = i & 32767, d = rem >> 8, c = rem & 255;
    wkT[i] = (f16)wkw[(kk << 15) + c * 128 + d];
  }
}

// ---------------------------------------------------------------------------
// Generic 64x64-tile f16 MFMA GEMM: out[m][n] = act(A[m][:] . BT[n][:] + bias[n])
// A: [M][KTOT] (f32 or f16), BT: [N][KTOT] f16.  4 waves, wave = 16 rows x 64 cols.
// ---------------------------------------------------------------------------
template <int KTOT, bool AF32, bool RELU>
__global__ __launch_bounds__(256) void k_gemm64(const void* __restrict__ Aptr,
                                                const f16* __restrict__ BT,
                                                const float* __restrict__ bias,
                                                f16* __restrict__ out, const int NT) {
  __shared__ __align__(16) f16 Al[64][40];  // +8 pad: kills ds_read bank conflicts
  __shared__ __align__(16) f16 Bl[64][40];
  const int m0 = blockIdx.x * 64;
  const int n0 = blockIdx.y * 64;
  const int t = threadIdx.x;
  const int w = t >> 6, l = t & 63, lr = l & 15, lg = l >> 4;
  const int arow = t >> 2, akq = (t & 3) * 8;
  f32x4 acc[4] = {};
  for (int ks = 0; ks < KTOT / 32; ++ks) {
    const int kc = ks * 32;
    __syncthreads();
    if constexpr (AF32) {
      const float* src = (const float*)Aptr + (size_t)(m0 + arow) * KTOT + kc + akq;
      float4 v0 = *(const float4*)src;
      float4 v1 = *(const float4*)(src + 4);
      f16x8 hv = {(f16)v0.x, (f16)v0.y, (f16)v0.z, (f16)v0.w,
                  (f16)v1.x, (f16)v1.y, (f16)v1.z, (f16)v1.w};
      *(f16x8*)&Al[arow][akq] = hv;
    } else {
      const f16* src = (const f16*)Aptr + (size_t)(m0 + arow) * KTOT + kc + akq;
      *(f16x8*)&Al[arow][akq] = *(const f16x8*)src;
    }
    *(f16x8*)&Bl[arow][akq] = *(const f16x8*)(BT + (size_t)(n0 + arow) * KTOT + kc + akq);
    __syncthreads();
    // A-frag: row = lane&15, k = 8*(lane>>4)+j ; B-frag: col = lane&15, same k
    f16x8 af = *(const f16x8*)&Al[16 * w + lr][lg * 8];
#pragma unroll
    for (int nt = 0; nt < 4; ++nt) {
      f16x8 bf = *(const f16x8*)&Bl[nt * 16 + lr][lg * 8];
      acc[nt] = __builtin_amdgcn_mfma_f32_16x16x32_f16(af, bf, acc[nt], 0, 0, 0);
    }
  }
  // C/D: col = lane&15, row = 4*(lane>>4)+r   [m89-verified layout]
#pragma unroll
  for (int nt = 0; nt < 4; ++nt) {
    const int n = n0 + nt * 16 + lr;
    const float bb = bias[n];
#pragma unroll
    for (int r = 0; r < 4; ++r) {
      const int m = m0 + 16 * w + lg * 4 + r;
      float v = acc[nt][r] + bb;
      if (RELU) v = fmaxf(v, 0.f);
      out[(size_t)m * NT + n] = (f16)v;
    }
  }
}

// ---------------------------------------------------------------------------
// K2: z = l2norm(h1 @ w2T + b2). N=128 so each wave owns full rows -> in-wave
// shfl row-norm. Writes z f32 (output) + z f16 (workspace).
// ---------------------------------------------------------------------------
__global__ __launch_bounds__(256) void k_enc2(const f16* __restrict__ A, const f16* __restrict__ BT,
                                              const float* __restrict__ bias,
                                              float* __restrict__ zf32, f16* __restrict__ zf16) {
  __shared__ __align__(16) f16 Al[64][40];
  __shared__ __align__(16) f16 Bl[128][40];
  const int m0 = blockIdx.x * 64;
  const int t = threadIdx.x;
  const int w = t >> 6, l = t & 63, lr = l & 15, lg = l >> 4;
  const int arow = t >> 2, akq = (t & 3) * 8;
  f32x4 acc[8] = {};
  for (int ks = 0; ks < 8; ++ks) {
    const int kc = ks * 32;
    __syncthreads();
    *(f16x8*)&Al[arow][akq] = *(const f16x8*)(A + (size_t)(m0 + arow) * 256 + kc + akq);
#pragma unroll
    for (int hh = 0; hh < 2; ++hh) {
      const int brow = arow + 64 * hh;
      *(f16x8*)&Bl[brow][akq] = *(const f16x8*)(BT + (size_t)brow * 256 + kc + akq);
    }
    __syncthreads();
    f16x8 af = *(const f16x8*)&Al[16 * w + lr][lg * 8];
#pragma unroll
    for (int nt = 0; nt < 8; ++nt) {
      f16x8 bf = *(const f16x8*)&Bl[nt * 16 + lr][lg * 8];
      acc[nt] = __builtin_amdgcn_mfma_f32_16x16x32_f16(af, bf, acc[nt], 0, 0, 0);
    }
  }
  float v[8][4];
#pragma unroll
  for (int nt = 0; nt < 8; ++nt) {
    const float bb = bias[nt * 16 + lr];
#pragma unroll
    for (int r = 0; r < 4; ++r) v[nt][r] = acc[nt][r] + bb;
  }
#pragma unroll
  for (int r = 0; r < 4; ++r) {
    float ss = 0.f;
#pragma unroll
    for (int nt = 0; nt < 8; ++nt) ss += v[nt][r] * v[nt][r];
    ss += __shfl_xor(ss, 1); ss += __shfl_xor(ss, 2); ss += __shfl_xor(ss, 4); ss += __shfl_xor(ss, 8);
    const float scl = 1.f / fmaxf(sqrtf(ss), 1e-12f);
    const int m = m0 + 16 * w + lg * 4 + r;
#pragma unroll
    for (int nt = 0; nt < 8; ++nt) {
      const int n = nt * 16 + lr;
      const float z = v[nt][r] * scl;
      zf32[(size_t)m * 128 + n] = z;
      zf16[(size_t)m * 128 + n] = (f16)z;
    }
  }
}

// ---------------------------------------------------------------------------
// K4: GRU scan. 128 blocks (one batch row each) x 768 threads.
// Thread o: gate g = o>>8 (0=r,1=z,2=n), column c = o&255.
// W_hh row (256 f16 = 32 uint4 = 128 VGPR) loaded once and PINNED live via
// empty asm "+v" barriers -> rematerialization of the global loads is
// illegal, regalloc must keep W resident (~150 regs < 168 cap @ 3 waves/EU).
// h broadcast: wave-uniform ds_read_b128 chunks (16B return, 1:4 LDS:fdot2).
// ---------------------------------------------------------------------------
__global__ __launch_bounds__(768, 3) void k_gru(const f16* __restrict__ gx, const f16* __restrict__ whh,
                                                const float* __restrict__ bhh,
                                                float* __restrict__ cout, f16* __restrict__ cf16) {
  __shared__ __align__(16) f16 h_lds[2][256];
  __shared__ float rz[2][256];
  const int b = blockIdx.x;
  const int o = threadIdx.x;
  const int g = o >> 8;
  const int c = o & 255;
  uint4 wv[32];
  {
    const uint4* wp = (const uint4*)(whh + (size_t)o * 256);
#pragma unroll
    for (int i = 0; i < 32; ++i) wv[i] = wp[i];
  }
  // --- residency pin: values become opaque, reload-rematerialization illegal
#pragma unroll
  for (int i = 0; i < 32; ++i)
    asm volatile("" : "+v"(wv[i].x), "+v"(wv[i].y), "+v"(wv[i].z), "+v"(wv[i].w));
  const float bh = bhh[o];
  if (o < 256) h_lds[0][o] = (f16)0.f;
  float h_own = 0.f;
  const f16* gxp = gx + (size_t)b * 256 * 768 + o;
  float* coutp = cout + (size_t)b * 256 * 256 + c;
  f16* cfp = cf16 + (size_t)b * 256 * 256 + c;
  __syncthreads();
#pragma unroll 1
  for (int tt = 0; tt < 256; ++tt) {
    const int cur = tt & 1;
    const float gxv = (float)gxp[tt * 768];
    float a0 = 0.f, a1 = 0.f, a2 = 0.f, a3 = 0.f;
    const uint4* hp = (const uint4*)(&h_lds[cur][0]);
#pragma unroll
    for (int i = 0; i < 32; ++i) {
      const uint4 hv = hp[i];  // wave-uniform address -> LDS broadcast, conflict-free
      a0 = __builtin_amdgcn_fdot2(u2h(wv[i].x), u2h(hv.x), a0, false);
      a1 = __builtin_amdgcn_fdot2(u2h(wv[i].y), u2h(hv.y), a1, false);
      a2 = __builtin_amdgcn_fdot2(u2h(wv[i].z), u2h(hv.z), a2, false);
      a3 = __builtin_amdgcn_fdot2(u2h(wv[i].w), u2h(hv.w), a3, false);
    }
    const float dot = (a0 + a1) + (a2 + a3) + bh;  // includes b_hh
    if (g < 2) rz[g][c] = sigm_(gxv + dot);
    __syncthreads();
    if (g == 2) {
      const float r = rz[0][c], zz = rz[1][c];
      const float n = tanh_(gxv + r * dot);
      const float hn = (1.f - zz) * n + zz * h_own;
      h_own = hn;
      h_lds[cur ^ 1][c] = (f16)hn;
      coutp[tt * 256] = hn;
      cfp[tt * 256] = (f16)hn;
    }
    __syncthreads();
  }
}

// ---------------------------------------------------------------------------
// K5: fused preds -> l2norm -> logits -> online LSE / pos / neg-max -> loss&acc.
// grid (tchunk=4, b=128, k=12), 256 threads. Never materializes logits.
// ---------------------------------------------------------------------------
__global__ __launch_bounds__(256) void k_cpc(const f16* __restrict__ cf16, const f16* __restrict__ zf16,
                                             const f16* __restrict__ wkT, const float* __restrict__ wkb,
                                             float* __restrict__ accb) {
  __shared__ __align__(16) f16 SMc[64 * 264];   // c-tile [64][264], reused as z-chunk [64][136]
  __shared__ __align__(16) f16 Bl[128][40];
  __shared__ __align__(16) f16 P[64][136];
  __shared__ float red[2];
  const int tc = blockIdx.x, b = blockIdx.y, kk = blockIdx.z;
  const int t0 = tc * 64;
  const int t = threadIdx.x;
  const int w = t >> 6, l = t & 63, lr = l & 15, lg = l >> 4;
  // ---- stage c tile (64 t-rows x 256 c = 8192 u32, 32 iters of 256) ----
  {
    const uint32_t* src = (const uint32_t*)(cf16 + ((size_t)b * 256 + t0) * 256);
    uint32_t* dst = (uint32_t*)SMc;
#pragma unroll
    for (int it = 0; it < 32; ++it) {
      const int idx = it * 256 + t, row = idx >> 7, cw = idx & 127;
      dst[row * 132 + cw] = src[row * 128 + cw];
    }
  }
  // ---- preds GEMM: (64 x 128) = c(64x256) @ WkT^T, K=256 ----
  f32x4 acc[8] = {};
  for (int ks = 0; ks < 8; ++ks) {
    __syncthreads();
    {
      const uint32_t* bsrc = (const uint32_t*)(wkT + ((size_t)kk << 15));
      uint32_t* bd = (uint32_t*)Bl;
#pragma unroll
      for (int it = 0; it < 8; ++it) {
        const int idx = it * 256 + t, row = idx >> 4, kw = idx & 15;
        bd[row * 20 + kw] = bsrc[row * 128 + ks * 16 + kw];
      }
    }
    __syncthreads();
    f16x8 af = *(const f16x8*)&SMc[(16 * w + lr) * 264 + ks * 32 + lg * 8];
#pragma unroll
    for (int nt = 0; nt < 8; ++nt) {
      f16x8 bf = *(const f16x8*)&Bl[nt * 16 + lr][lg * 8];
      acc[nt] = __builtin_amdgcn_mfma_f32_16x16x32_f16(af, bf, acc[nt], 0, 0, 0);
    }
  }
  // ---- preds epilogue: bias + row l2norm -> P (f16) ----
  {
    float v[8][4];
#pragma unroll
    for (int nt = 0; nt < 8; ++nt) {
      const float bb = wkb[kk * 128 + nt * 16 + lr];
#pragma unroll
      for (int r = 0; r < 4; ++r) v[nt][r] = acc[nt][r] + bb;
    }
#pragma unroll
    for (int r = 0; r < 4; ++r) {
      float ss = 0.f;
#pragma unroll
      for (int nt = 0; nt < 8; ++nt) ss += v[nt][r] * v[nt][r];
      ss += __shfl_xor(ss, 1); ss += __shfl_xor(ss, 2); ss += __shfl_xor(ss, 4); ss += __shfl_xor(ss, 8);
      const float scl = 1.f / fmaxf(sqrtf(ss), 1e-12f);
#pragma unroll
      for (int nt = 0; nt < 8; ++nt)
        P[16 * w + lg * 4 + r][nt * 16 + lr] = (f16)(v[nt][r] * scl);
    }
  }
  __syncthreads();
  // ---- logits + online LSE/pos/negmax over 4 s-chunks of 64 ----
  float m_run[4], s_run[4], pos_v[4], neg_m[4];
#pragma unroll
  for (int r = 0; r < 4; ++r) { m_run[r] = -1e30f; s_run[r] = 0.f; pos_v[r] = -1e30f; neg_m[r] = -1e30f; }
  for (int sc = 0; sc < 4; ++sc) {
    __syncthreads();
    {
      const uint32_t* zsrc = (const uint32_t*)(zf16 + ((size_t)b * 256 + sc * 64) * 128);
      uint32_t* zd = (uint32_t*)SMc;
#pragma unroll
      for (int it = 0; it < 16; ++it) {
        const int idx = it * 256 + t, row = idx >> 6, cw = idx & 63;
        zd[row * 68 + cw] = zsrc[row * 64 + cw];
      }
    }
    __syncthreads();
    f32x4 sa[4] = {};
#pragma unroll
    for (int ks = 0; ks < 4; ++ks) {
      f16x8 af = *(const f16x8*)&P[16 * w + lr][ks * 32 + lg * 8];
#pragma unroll
      for (int nt = 0; nt < 4; ++nt) {
        f16x8 bf = *(const f16x8*)&SMc[(nt * 16 + lr) * 136 + ks * 32 + lg * 8];
        sa[nt] = __builtin_amdgcn_mfma_f32_16x16x32_f16(af, bf, sa[nt], 0, 0, 0);
      }
    }
#pragma unroll
    for (int r = 0; r < 4; ++r) {
      const int trow = t0 + 16 * w + lg * 4 + r;
      const int pos_s = trow + kk + 1;
      float vv[4];
#pragma unroll
      for (int nt = 0; nt < 4; ++nt) vv[nt] = sa[nt][r] * 10.f;  // 1/TEMP
      float cm = fmaxf(fmaxf(vv[0], vv[1]), fmaxf(vv[2], vv[3]));
      cm = fmaxf(cm, __shfl_xor(cm, 1)); cm = fmaxf(cm, __shfl_xor(cm, 2));
      cm = fmaxf(cm, __shfl_xor(cm, 4)); cm = fmaxf(cm, __shfl_xor(cm, 8));
      const float nm = fmaxf(m_run[r], cm);
      float ps = __expf(vv[0] - nm) + __expf(vv[1] - nm) + __expf(vv[2] - nm) + __expf(vv[3] - nm);
      ps += __shfl_xor(ps, 1); ps += __shfl_xor(ps, 2); ps += __shfl_xor(ps, 4); ps += __shfl_xor(ps, 8);
      s_run[r] = s_run[r] * __expf(m_run[r] - nm) + ps;
      m_run[r] = nm;
      const int sbase = sc * 64 + lr;
#pragma unroll
      for (int nt = 0; nt < 4; ++nt) {
        const int s = sbase + nt * 16;
        if (s == pos_s) pos_v[r] = vv[nt];
        else neg_m[r] = fmaxf(neg_m[r], vv[nt]);
      }
    }
  }
  // ---- finalize ----
  __syncthreads();
  if (t == 0) { red[0] = 0.f; red[1] = 0.f; }
  __syncthreads();
  float lsum = 0.f, csum = 0.f;
#pragma unroll
  for (int r = 0; r < 4; ++r) {
    float pv = pos_v[r], ng = neg_m[r];
    pv = fmaxf(pv, __shfl_xor(pv, 1)); pv = fmaxf(pv, __shfl_xor(pv, 2));
    pv = fmaxf(pv, __shfl_xor(pv, 4)); pv = fmaxf(pv, __shfl_xor(pv, 8));
    ng = fmaxf(ng, __shfl_xor(ng, 1)); ng = fmaxf(ng, __shfl_xor(ng, 2));
    ng = fmaxf(ng, __shfl_xor(ng, 4)); ng = fmaxf(ng, __shfl_xor(ng, 8));
    const int trow = t0 + 16 * w + lg * 4 + r;
    if (lr == 0 && trow < 244) {
      const float lse = m_run[r] + __logf(s_run[r]);
      lsum += lse - pv;
      csum += (pv >= ng) ? 1.f : 0.f;
    }
  }
  if (lr == 0) { atomicAdd(&red[0], lsum); atomicAdd(&red[1], csum); }
  __syncthreads();
  if (t == 0) { atomicAdd(&accb[0], red[0]); atomicAdd(&accb[1], red[1]); }
}

__global__ void k_fin(const float* __restrict__ accb, float* __restrict__ out) {
  out[0] = accb[0] * (1.0f / NTOT_LOSS);
  out[1] = accb[1] * (100.0f / NTOT_LOSS);
}

// ---------------------------------------------------------------------------
extern "C" void kernel_launch(void* const* d_in, const int* in_sizes, int n_in,
                              void* d_out, int out_size, void* d_ws, size_t ws_size,
                              hipStream_t stream) {
  (void)in_sizes; (void)n_in; (void)out_size; (void)ws_size;
  const float* rr  = (const float*)d_in[0];
  const float* w1  = (const float*)d_in[1];
  const float* b1  = (const float*)d_in[2];
  const float* w2  = (const float*)d_in[3];
  const float* b2  = (const float*)d_in[4];
  const float* wih = (const float*)d_in[5];
  const float* whh = (const float*)d_in[6];
  const float* bih = (const float*)d_in[7];
  const float* bhh = (const float*)d_in[8];
  const float* wkw = (const float*)d_in[9];
  const float* wkb = (const float*)d_in[10];
  float* out = (float*)d_out;
  char* ws = (char*)d_ws;

  // workspace layout (77.1 MB total)
  const size_t GX_B = (size_t)32768 * 768 * 2;  // 50,331,648
  f16* gx   = (f16*)ws;
  f16* h1   = (f16*)ws;  // alias: h1 (16.8MB) dead before gx is written
  f16* zf16 = (f16*)(ws + GX_B);
  f16* cf16 = (f16*)(ws + GX_B + 8388608);
  f16* w1T  = (f16*)(ws + GX_B + 8388608 + 16777216);
  f16* w2T  = w1T + 65536;
  f16* wihF = w2T + 32768;
  f16* whhF = wihF + 98304;
  f16* wkT  = whhF + 196608;
  float* accb = (float*)(wkT + 393216);

  float* zf32 = out + 2;
  float* cf32 = out + 2 + 4194304;

  k_prep<<<256, 256, 0, stream>>>(w1, w2, wih, whh, wkw, w1T, w2T, wihF, whhF, wkT, accb);
  k_gemm64<256, true, true><<<dim3(512, 4), 256, 0, stream>>>(rr, w1T, b1, h1, 256);
  k_enc2<<<dim3(512), 256, 0, stream>>>(h1, w2T, b2, zf32, zf16);
  k_gemm64<128, false, false><<<dim3(512, 12), 256, 0, stream>>>(zf16, wihF, bih, gx, 768);
  k_gru<<<128, 768, 0, stream>>>(gx, whhF, bhh, cf32, cf16);
  k_cpc<<<dim3(4, 128, 12), 256, 0, stream>>>(cf16, zf16, wkT, wkb, accb);
  k_fin<<<1, 1, 0, stream>>>(accb, out);
}

// Round 5
// 655.577 us; speedup vs baseline: 1.0867x; 1.0019x over previous
//
#include <hip/hip_runtime.h>
#include <stdint.h>

// ============================================================================
// CPC forward on MI355X (gfx950).
// Pipeline: k_prep (f16 weight convert + transpose, zero accumulators)
//   -> k_gemm64<256,f32A,relu>  h1 = relu(rr @ w1 + b1)            [MFMA f16]
//   -> k_enc2                   z  = l2norm(h1 @ w2 + b2)          [MFMA f16]
//   -> k_gemm64<128,f16A,->     gx = z @ W_ih^T + b_ih             [MFMA f16]
//   -> k_gru                    sequential scan, W_hh pinned in VGPRs
//   -> k_cpc                    fused preds->l2norm->logits->online LSE/acc
//   -> k_fin                    scalar finalize
// Precision: f16 storage/operands, f32 accumulation everywhere.
// R2-R4 lesson: allocator kept VGPR~80 (occupancy heuristic targets >3
// waves/EU since launch_bounds 2nd arg is only a MIN) -> W_hh either
// rematerialized from L2 (R2: 328us, 39TB/s = L2 ceiling) or spilled to
// scratch (R4: 389us). Runtime occupancy is fixed anyway (128 blocks on 256
// CUs = 3 waves/SIMD). R5: clamp BOTH sides via amdgpu_waves_per_eu(3,3)
// -> VGPR budget 170, W (128 regs) + temps fits; pin asm still forbids
// remat. Expected ~900 cyc/step -> ~96us.
// ============================================================================

typedef _Float16 f16;
typedef __attribute__((ext_vector_type(2))) _Float16 f16x2;
typedef __attribute__((ext_vector_type(8))) _Float16 f16x8;
typedef __attribute__((ext_vector_type(4))) float f32x4;

__device__ __forceinline__ f16x2 u2h(unsigned int x) { return __builtin_bit_cast(f16x2, x); }
__device__ __forceinline__ float sigm_(float x) { return __builtin_amdgcn_rcpf(1.f + __expf(-x)); }
__device__ __forceinline__ float tanh_(float x) { return 1.f - 2.f * __builtin_amdgcn_rcpf(__expf(2.f * x) + 1.f); }

#define NTOT_LOSS 374784.0f  // 12 * 128 * 244

// ---------------------------------------------------------------------------
// K0: convert weights to f16 (transposing where the GEMMs want [N][K]),
//     zero the loss/accuracy accumulators.
// ---------------------------------------------------------------------------
__global__ void k_prep(const float* __restrict__ w1, const float* __restrict__ w2,
                       const float* __restrict__ wih, const float* __restrict__ whh,
                       const float* __restrict__ wkw,
                       f16* __restrict__ w1T, f16* __restrict__ w2T, f16* __restrict__ wihF,
                       f16* __restrict__ whhF, f16* __restrict__ wkT, float* __restrict__ accb) {
  const int stride = gridDim.x * blockDim.x;
  const int tid = blockIdx.x * blockDim.x + threadIdx.x;
  if (tid == 0) { accb[0] = 0.f; accb[1] = 0.f; }
  // w1 (256k x 256n) -> w1T[n][k]
  for (int i = tid; i < 65536; i += stride) { int n = i >> 8, k = i & 255; w1T[i] = (f16)w1[k * 256 + n]; }
  // w2 (256k x 128n) -> w2T[n][k]  (n<128, k<256)
  for (int i = tid; i < 32768; i += stride) { int n = i >> 8, k = i & 255; w2T[i] = (f16)w2[k * 128 + n]; }
  // W_ih (768 x 128) already [N][K] for gx GEMM
  for (int i = tid; i < 98304; i += stride) wihF[i] = (f16)wih[i];
  // W_hh (768 x 256) row-major, consumed row-per-thread in k_gru
  for (int i = tid; i < 196608; i += stride) whhF[i] = (f16)whh[i];
  // Wk_w (12,256c,128d) -> wkT[kk][d][c]
  for (int i = tid; i < 393216; i += stride) {
    int kk = i >> 15, rem = i & 32767, d = rem >> 8, c = rem & 255;
    wkT[i] = (f16)wkw[(kk << 15) + c * 128 + d];
  }
}

// ---------------------------------------------------------------------------
// Generic 64x64-tile f16 MFMA GEMM: out[m][n] = act(A[m][:] . BT[n][:] + bias[n])
// A: [M][KTOT] (f32 or f16), BT: [N][KTOT] f16.  4 waves, wave = 16 rows x 64 cols.
// ---------------------------------------------------------------------------
template <int KTOT, bool AF32, bool RELU>
__global__ __launch_bounds__(256) void k_gemm64(const void* __restrict__ Aptr,
                                                const f16* __restrict__ BT,
                                                const float* __restrict__ bias,
                                                f16* __restrict__ out, const int NT) {
  __shared__ __align__(16) f16 Al[64][40];  // +8 pad: kills ds_read bank conflicts
  __shared__ __align__(16) f16 Bl[64][40];
  const int m0 = blockIdx.x * 64;
  const int n0 = blockIdx.y * 64;
  const int t = threadIdx.x;
  const int w = t >> 6, l = t & 63, lr = l & 15, lg = l >> 4;
  const int arow = t >> 2, akq = (t & 3) * 8;
  f32x4 acc[4] = {};
  for (int ks = 0; ks < KTOT / 32; ++ks) {
    const int kc = ks * 32;
    __syncthreads();
    if constexpr (AF32) {
      const float* src = (const float*)Aptr + (size_t)(m0 + arow) * KTOT + kc + akq;
      float4 v0 = *(const float4*)src;
      float4 v1 = *(const float4*)(src + 4);
      f16x8 hv = {(f16)v0.x, (f16)v0.y, (f16)v0.z, (f16)v0.w,
                  (f16)v1.x, (f16)v1.y, (f16)v1.z, (f16)v1.w};
      *(f16x8*)&Al[arow][akq] = hv;
    } else {
      const f16* src = (const f16*)Aptr + (size_t)(m0 + arow) * KTOT + kc + akq;
      *(f16x8*)&Al[arow][akq] = *(const f16x8*)src;
    }
    *(f16x8*)&Bl[arow][akq] = *(const f16x8*)(BT + (size_t)(n0 + arow) * KTOT + kc + akq);
    __syncthreads();
    // A-frag: row = lane&15, k = 8*(lane>>4)+j ; B-frag: col = lane&15, same k
    f16x8 af = *(const f16x8*)&Al[16 * w + lr][lg * 8];
#pragma unroll
    for (int nt = 0; nt < 4; ++nt) {
      f16x8 bf = *(const f16x8*)&Bl[nt * 16 + lr][lg * 8];
      acc[nt] = __builtin_amdgcn_mfma_f32_16x16x32_f16(af, bf, acc[nt], 0, 0, 0);
    }
  }
  // C/D: col = lane&15, row = 4*(lane>>4)+r   [m89-verified layout]
#pragma unroll
  for (int nt = 0; nt < 4; ++nt) {
    const int n = n0 + nt * 16 + lr;
    const float bb = bias[n];
#pragma unroll
    for (int r = 0; r < 4; ++r) {
      const int m = m0 + 16 * w + lg * 4 + r;
      float v = acc[nt][r] + bb;
      if (RELU) v = fmaxf(v, 0.f);
      out[(size_t)m * NT + n] = (f16)v;
    }
  }
}

// ---------------------------------------------------------------------------
// K2: z = l2norm(h1 @ w2T + b2). N=128 so each wave owns full rows -> in-wave
// shfl row-norm. Writes z f32 (output) + z f16 (workspace).
// ---------------------------------------------------------------------------
__global__ __launch_bounds__(256) void k_enc2(const f16* __restrict__ A, const f16* __restrict__ BT,
                                              const float* __restrict__ bias,
                                              float* __restrict__ zf32, f16* __restrict__ zf16) {
  __shared__ __align__(16) f16 Al[64][40];
  __shared__ __align__(16) f16 Bl[128][40];
  const int m0 = blockIdx.x * 64;
  const int t = threadIdx.x;
  const int w = t >> 6, l = t & 63, lr = l & 15, lg = l >> 4;
  const int arow = t >> 2, akq = (t & 3) * 8;
  f32x4 acc[8] = {};
  for (int ks = 0; ks < 8; ++ks) {
    const int kc = ks * 32;
    __syncthreads();
    *(f16x8*)&Al[arow][akq] = *(const f16x8*)(A + (size_t)(m0 + arow) * 256 + kc + akq);
#pragma unroll
    for (int hh = 0; hh < 2; ++hh) {
      const int brow = arow + 64 * hh;
      *(f16x8*)&Bl[brow][akq] = *(const f16x8*)(BT + (size_t)brow * 256 + kc + akq);
    }
    __syncthreads();
    f16x8 af = *(const f16x8*)&Al[16 * w + lr][lg * 8];
#pragma unroll
    for (int nt = 0; nt < 8; ++nt) {
      f16x8 bf = *(const f16x8*)&Bl[nt * 16 + lr][lg * 8];
      acc[nt] = __builtin_amdgcn_mfma_f32_16x16x32_f16(af, bf, acc[nt], 0, 0, 0);
    }
  }
  float v[8][4];
#pragma unroll
  for (int nt = 0; nt < 8; ++nt) {
    const float bb = bias[nt * 16 + lr];
#pragma unroll
    for (int r = 0; r < 4; ++r) v[nt][r] = acc[nt][r] + bb;
  }
#pragma unroll
  for (int r = 0; r < 4; ++r) {
    float ss = 0.f;
#pragma unroll
    for (int nt = 0; nt < 8; ++nt) ss += v[nt][r] * v[nt][r];
    ss += __shfl_xor(ss, 1); ss += __shfl_xor(ss, 2); ss += __shfl_xor(ss, 4); ss += __shfl_xor(ss, 8);
    const float scl = 1.f / fmaxf(sqrtf(ss), 1e-12f);
    const int m = m0 + 16 * w + lg * 4 + r;
#pragma unroll
    for (int nt = 0; nt < 8; ++nt) {
      const int n = nt * 16 + lr;
      const float z = v[nt][r] * scl;
      zf32[(size_t)m * 128 + n] = z;
      zf16[(size_t)m * 128 + n] = (f16)z;
    }
  }
}

// ---------------------------------------------------------------------------
// K4: GRU scan. 128 blocks (one batch row each) x 768 threads.
// Thread o: gate g = o>>8 (0=r,1=z,2=n), column c = o&255.
// W_hh row (256 f16 = 32 uint4 = 128 VGPR) loaded once, PINNED live via
// empty asm "+v" barriers. amdgpu_waves_per_eu(3,3) clamps the allocator's
// occupancy target to the runtime reality (128 blocks / 256 CUs -> exactly
// 3 waves/SIMD), giving a 170-VGPR budget so W actually stays resident.
// h broadcast: wave-uniform ds_read_b128 (16B broadcast, conflict-free).
// ---------------------------------------------------------------------------
__global__ __attribute__((amdgpu_flat_work_group_size(768, 768), amdgpu_waves_per_eu(3, 3)))
void k_gru(const f16* __restrict__ gx, const f16* __restrict__ whh,
           const float* __restrict__ bhh,
           float* __restrict__ cout, f16* __restrict__ cf16) {
  __shared__ __align__(16) f16 h_lds[2][256];
  __shared__ float rz[2][256];
  const int b = blockIdx.x;
  const int o = threadIdx.x;
  const int g = o >> 8;
  const int c = o & 255;
  uint4 wv[32];
  {
    const uint4* wp = (const uint4*)(whh + (size_t)o * 256);
#pragma unroll
    for (int i = 0; i < 32; ++i) wv[i] = wp[i];
  }
  // --- residency pin: values become opaque, reload-rematerialization illegal
#pragma unroll
  for (int i = 0; i < 32; ++i)
    asm volatile("" : "+v"(wv[i].x), "+v"(wv[i].y), "+v"(wv[i].z), "+v"(wv[i].w));
  const float bh = bhh[o];
  if (o < 256) h_lds[0][o] = (f16)0.f;
  float h_own = 0.f;
  const f16* gxp = gx + (size_t)b * 256 * 768 + o;
  float* coutp = cout + (size_t)b * 256 * 256 + c;
  f16* cfp = cf16 + (size_t)b * 256 * 256 + c;
  __syncthreads();
#pragma unroll 1
  for (int tt = 0; tt < 256; ++tt) {
    const int cur = tt & 1;
    const float gxv = (float)gxp[tt * 768];
    float a0 = 0.f, a1 = 0.f, a2 = 0.f, a3 = 0.f;
    const uint4* hp = (const uint4*)(&h_lds[cur][0]);
#pragma unroll
    for (int i = 0; i < 32; ++i) {
      const uint4 hv = hp[i];  // wave-uniform address -> LDS broadcast, conflict-free
      a0 = __builtin_amdgcn_fdot2(u2h(wv[i].x), u2h(hv.x), a0, false);
      a1 = __builtin_amdgcn_fdot2(u2h(wv[i].y), u2h(hv.y), a1, false);
      a2 = __builtin_amdgcn_fdot2(u2h(wv[i].z), u2h(hv.z), a2, false);
      a3 = __builtin_amdgcn_fdot2(u2h(wv[i].w), u2h(hv.w), a3, false);
    }
    const float dot = (a0 + a1) + (a2 + a3) + bh;  // includes b_hh
    if (g < 2) rz[g][c] = sigm_(gxv + dot);
    __syncthreads();
    if (g == 2) {
      const float r = rz[0][c], zz = rz[1][c];
      const float n = tanh_(gxv + r * dot);
      const float hn = (1.f - zz) * n + zz * h_own;
      h_own = hn;
      h_lds[cur ^ 1][c] = (f16)hn;
      coutp[tt * 256] = hn;
      cfp[tt * 256] = (f16)hn;
    }
    __syncthreads();
  }
}

// ---------------------------------------------------------------------------
// K5: fused preds -> l2norm -> logits -> online LSE / pos / neg-max -> loss&acc.
// grid (tchunk=4, b=128, k=12), 256 threads. Never materializes logits.
// ---------------------------------------------------------------------------
__global__ __launch_bounds__(256) void k_cpc(const f16* __restrict__ cf16, const f16* __restrict__ zf16,
                                             const f16* __restrict__ wkT, const float* __restrict__ wkb,
                                             float* __restrict__ accb) {
  __shared__ __align__(16) f16 SMc[64 * 264];   // c-tile [64][264], reused as z-chunk [64][136]
  __shared__ __align__(16) f16 Bl[128][40];
  __shared__ __align__(16) f16 P[64][136];
  __shared__ float red[2];
  const int tc = blockIdx.x, b = blockIdx.y, kk = blockIdx.z;
  const int t0 = tc * 64;
  const int t = threadIdx.x;
  const int w = t >> 6, l = t & 63, lr = l & 15, lg = l >> 4;
  // ---- stage c tile (64 t-rows x 256 c = 8192 u32, 32 iters of 256) ----
  {
    const uint32_t* src = (const uint32_t*)(cf16 + ((size_t)b * 256 + t0) * 256);
    uint32_t* dst = (uint32_t*)SMc;
#pragma unroll
    for (int it = 0; it < 32; ++it) {
      const int idx = it * 256 + t, row = idx >> 7, cw = idx & 127;
      dst[row * 132 + cw] = src[row * 128 + cw];
    }
  }
  // ---- preds GEMM: (64 x 128) = c(64x256) @ WkT^T, K=256 ----
  f32x4 acc[8] = {};
  for (int ks = 0; ks < 8; ++ks) {
    __syncthreads();
    {
      const uint32_t* bsrc = (const uint32_t*)(wkT + ((size_t)kk << 15));
      uint32_t* bd = (uint32_t*)Bl;
#pragma unroll
      for (int it = 0; it < 8; ++it) {
        const int idx = it * 256 + t, row = idx >> 4, kw = idx & 15;
        bd[row * 20 + kw] = bsrc[row * 128 + ks * 16 + kw];
      }
    }
    __syncthreads();
    f16x8 af = *(const f16x8*)&SMc[(16 * w + lr) * 264 + ks * 32 + lg * 8];
#pragma unroll
    for (int nt = 0; nt < 8; ++nt) {
      f16x8 bf = *(const f16x8*)&Bl[nt * 16 + lr][lg * 8];
      acc[nt] = __builtin_amdgcn_mfma_f32_16x16x32_f16(af, bf, acc[nt], 0, 0, 0);
    }
  }
  // ---- preds epilogue: bias + row l2norm -> P (f16) ----
  {
    float v[8][4];
#pragma unroll
    for (int nt = 0; nt < 8; ++nt) {
      const float bb = wkb[kk * 128 + nt * 16 + lr];
#pragma unroll
      for (int r = 0; r < 4; ++r) v[nt][r] = acc[nt][r] + bb;
    }
#pragma unroll
    for (int r = 0; r < 4; ++r) {
      float ss = 0.f;
#pragma unroll
      for (int nt = 0; nt < 8; ++nt) ss += v[nt][r] * v[nt][r];
      ss += __shfl_xor(ss, 1); ss += __shfl_xor(ss, 2); ss += __shfl_xor(ss, 4); ss += __shfl_xor(ss, 8);
      const float scl = 1.f / fmaxf(sqrtf(ss), 1e-12f);
#pragma unroll
      for (int nt = 0; nt < 8; ++nt)
        P[16 * w + lg * 4 + r][nt * 16 + lr] = (f16)(v[nt][r] * scl);
    }
  }
  __syncthreads();
  // ---- logits + online LSE/pos/negmax over 4 s-chunks of 64 ----
  float m_run[4], s_run[4], pos_v[4], neg_m[4];
#pragma unroll
  for (int r = 0; r < 4; ++r) { m_run[r] = -1e30f; s_run[r] = 0.f; pos_v[r] = -1e30f; neg_m[r] = -1e30f; }
  for (int sc = 0; sc < 4; ++sc) {
    __syncthreads();
    {
      const uint32_t* zsrc = (const uint32_t*)(zf16 + ((size_t)b * 256 + sc * 64) * 128);
      uint32_t* zd = (uint32_t*)SMc;
#pragma unroll
      for (int it = 0; it < 16; ++it) {
        const int idx = it * 256 + t, row = idx >> 6, cw = idx & 63;
        zd[row * 68 + cw] = zsrc[row * 64 + cw];
      }
    }
    __syncthreads();
    f32x4 sa[4] = {};
#pragma unroll
    for (int ks = 0; ks < 4; ++ks) {
      f16x8 af = *(const f16x8*)&P[16 * w + lr][ks * 32 + lg * 8];
#pragma unroll
      for (int nt = 0; nt < 4; ++nt) {
        f16x8 bf = *(const f16x8*)&SMc[(nt * 16 + lr) * 136 + ks * 32 + lg * 8];
        sa[nt] = __builtin_amdgcn_mfma_f32_16x16x32_f16(af, bf, sa[nt], 0, 0, 0);
      }
    }
#pragma unroll
    for (int r = 0; r < 4; ++r) {
      const int trow = t0 + 16 * w + lg * 4 + r;
      const int pos_s = trow + kk + 1;
      float vv[4];
#pragma unroll
      for (int nt = 0; nt < 4; ++nt) vv[nt] = sa[nt][r] * 10.f;  // 1/TEMP
      float cm = fmaxf(fmaxf(vv[0], vv[1]), fmaxf(vv[2], vv[3]));
      cm = fmaxf(cm, __shfl_xor(cm, 1)); cm = fmaxf(cm, __shfl_xor(cm, 2));
      cm = fmaxf(cm, __shfl_xor(cm, 4)); cm = fmaxf(cm, __shfl_xor(cm, 8));
      const float nm = fmaxf(m_run[r], cm);
      float ps = __expf(vv[0] - nm) + __expf(vv[1] - nm) + __expf(vv[2] - nm) + __expf(vv[3] - nm);
      ps += __shfl_xor(ps, 1); ps += __shfl_xor(ps, 2); ps += __shfl_xor(ps, 4); ps += __shfl_xor(ps, 8);
      s_run[r] = s_run[r] * __expf(m_run[r] - nm) + ps;
      m_run[r] = nm;
      const int sbase = sc * 64 + lr;
#pragma unroll
      for (int nt = 0; nt < 4; ++nt) {
        const int s = sbase + nt * 16;
        if (s == pos_s) pos_v[r] = vv[nt];
        else neg_m[r] = fmaxf(neg_m[r], vv[nt]);
      }
    }
  }
  // ---- finalize ----
  __syncthreads();
  if (t == 0) { red[0] = 0.f; red[1] = 0.f; }
  __syncthreads();
  float lsum = 0.f, csum = 0.f;
#pragma unroll
  for (int r = 0; r < 4; ++r) {
    float pv = pos_v[r], ng = neg_m[r];
    pv = fmaxf(pv, __shfl_xor(pv, 1)); pv = fmaxf(pv, __shfl_xor(pv, 2));
    pv = fmaxf(pv, __shfl_xor(pv, 4)); pv = fmaxf(pv, __shfl_xor(pv, 8));
    ng = fmaxf(ng, __shfl_xor(ng, 1)); ng = fmaxf(ng, __shfl_xor(ng, 2));
    ng = fmaxf(ng, __shfl_xor(ng, 4)); ng = fmaxf(ng, __shfl_xor(ng, 8));
    const int trow = t0 + 16 * w + lg * 4 + r;
    if (lr == 0 && trow < 244) {
      const float lse = m_run[r] + __logf(s_run[r]);
      lsum += lse - pv;
      csum += (pv >= ng) ? 1.f : 0.f;
    }
  }
  if (lr == 0) { atomicAdd(&red[0], lsum); atomicAdd(&red[1], csum); }
  __syncthreads();
  if (t == 0) { atomicAdd(&accb[0], red[0]); atomicAdd(&accb[1], red[1]); }
}

__global__ void k_fin(const float* __restrict__ accb, float* __restrict__ out) {
  out[0] = accb[0] * (1.0f / NTOT_LOSS);
  out[1] = accb[1] * (100.0f / NTOT_LOSS);
}

// ---------------------------------------------------------------------------
extern "C" void kernel_launch(void* const* d_in, const int* in_sizes, int n_in,
                              void* d_out, int out_size, void* d_ws, size_t ws_size,
                              hipStream_t stream) {
  (void)in_sizes; (void)n_in; (void)out_size; (void)ws_size;
  const float* rr  = (const float*)d_in[0];
  const float* w1  = (const float*)d_in[1];
  const float* b1  = (const float*)d_in[2];
  const float* w2  = (const float*)d_in[3];
  const float* b2  = (const float*)d_in[4];
  const float* wih = (const float*)d_in[5];
  const float* whh = (const float*)d_in[6];
  const float* bih = (const float*)d_in[7];
  const float* bhh = (const float*)d_in[8];
  const float* wkw = (const float*)d_in[9];
  const float* wkb = (const float*)d_in[10];
  float* out = (float*)d_out;
  char* ws = (char*)d_ws;

  // workspace layout (77.1 MB total)
  const size_t GX_B = (size_t)32768 * 768 * 2;  // 50,331,648
  f16* gx   = (f16*)ws;
  f16* h1   = (f16*)ws;  // alias: h1 (16.8MB) dead before gx is written
  f16* zf16 = (f16*)(ws + GX_B);
  f16* cf16 = (f16*)(ws + GX_B + 8388608);
  f16* w1T  = (f16*)(ws + GX_B + 8388608 + 16777216);
  f16* w2T  = w1T + 65536;
  f16* wihF = w2T + 32768;
  f16* whhF = wihF + 98304;
  f16* wkT  = whhF + 196608;
  float* accb = (float*)(wkT + 393216);

  float* zf32 = out + 2;
  float* cf32 = out + 2 + 4194304;

  k_prep<<<256, 256, 0, stream>>>(w1, w2, wih, whh, wkw, w1T, w2T, wihF, whhF, wkT, accb);
  k_gemm64<256, true, true><<<dim3(512, 4), 256, 0, stream>>>(rr, w1T, b1, h1, 256);
  k_enc2<<<dim3(512), 256, 0, stream>>>(h1, w2T, b2, zf32, zf16);
  k_gemm64<128, false, false><<<dim3(512, 12), 256, 0, stream>>>(zf16, wihF, bih, gx, 768);
  k_gru<<<128, 768, 0, stream>>>(gx, whhF, bhh, cf32, cf16);
  k_cpc<<<dim3(4, 128, 12), 256, 0, stream>>>(cf16, zf16, wkT, wkb, accb);
  k_fin<<<1, 1, 0, stream>>>(accb, out);
}

// Round 6
// 591.379 us; speedup vs baseline: 1.2047x; 1.1086x over previous
//
#include <hip/hip_runtime.h>
#include <stdint.h>

// ============================================================================
// CPC forward on MI355X (gfx950).
// Pipeline: k_prep (f16 weight convert + transpose, zero accumulators)
//   -> k_gemm64<256,f32A,relu>  h1 = relu(rr @ w1 + b1)            [MFMA f16]
//   -> k_enc2                   z  = l2norm(h1 @ w2 + b2)          [MFMA f16]
//   -> k_gemm64<128,f16A,->     gx = z @ W_ih^T + b_ih             [MFMA f16]
//   -> k_gru                    sequential scan, W_hh pinned in VGPRs
//   -> k_cpc                    fused preds->l2norm->logits->online LSE/acc
//   -> k_fin                    scalar finalize
// Precision: f16 storage/operands, f32 accumulation everywhere.
// R2-R5 saga: allocator refuses to keep W_hh (128 VGPRs/thread) resident.
//   R2: remat global loads -> L2-BW bound (328us). R3: readlane doubled VALU
//   (444us). R4/R5: per-element asm pins -> allocator spilled to scratch
//   between pins (VGPR=80, 387us): each separate asm only forces ITS 4 dwords
//   live at ITS point. R6: ONE asm per timestep with eight 512-bit VReg_512
//   operands -> all 128 dwords must be simultaneously live every iteration;
//   spill-around cost (256 mem ops/step) makes residency the only sane
//   allocation. waves_per_eu(3,3) gives the 170-reg budget (~150 needed).
// ============================================================================

typedef _Float16 f16;
typedef __attribute__((ext_vector_type(2))) _Float16 f16x2;
typedef __attribute__((ext_vector_type(8))) _Float16 f16x8;
typedef __attribute__((ext_vector_type(4))) float f32x4;
typedef __attribute__((ext_vector_type(16))) unsigned int u32x16;

__device__ __forceinline__ f16x2 u2h(unsigned int x) { return __builtin_bit_cast(f16x2, x); }
__device__ __forceinline__ float sigm_(float x) { return __builtin_amdgcn_rcpf(1.f + __expf(-x)); }
__device__ __forceinline__ float tanh_(float x) { return 1.f - 2.f * __builtin_amdgcn_rcpf(__expf(2.f * x) + 1.f); }

#define NTOT_LOSS 374784.0f  // 12 * 128 * 244

// ---------------------------------------------------------------------------
// K0: convert weights to f16 (transposing where the GEMMs want [N][K]),
//     zero the loss/accuracy accumulators.
// ---------------------------------------------------------------------------
__global__ void k_prep(const float* __restrict__ w1, const float* __restrict__ w2,
                       const float* __restrict__ wih, const float* __restrict__ whh,
                       const float* __restrict__ wkw,
                       f16* __restrict__ w1T, f16* __restrict__ w2T, f16* __restrict__ wihF,
                       f16* __restrict__ whhF, f16* __restrict__ wkT, float* __restrict__ accb) {
  const int stride = gridDim.x * blockDim.x;
  const int tid = blockIdx.x * blockDim.x + threadIdx.x;
  if (tid == 0) { accb[0] = 0.f; accb[1] = 0.f; }
  // w1 (256k x 256n) -> w1T[n][k]
  for (int i = tid; i < 65536; i += stride) { int n = i >> 8, k = i & 255; w1T[i] = (f16)w1[k * 256 + n]; }
  // w2 (256k x 128n) -> w2T[n][k]  (n<128, k<256)
  for (int i = tid; i < 32768; i += stride) { int n = i >> 8, k = i & 255; w2T[i] = (f16)w2[k * 128 + n]; }
  // W_ih (768 x 128) already [N][K] for gx GEMM
  for (int i = tid; i < 98304; i += stride) wihF[i] = (f16)wih[i];
  // W_hh (768 x 256) row-major, consumed row-per-thread in k_gru
  for (int i = tid; i < 196608; i += stride) whhF[i] = (f16)whh[i];
  // Wk_w (12,256c,128d) -> wkT[kk][d][c]
  for (int i = tid; i < 393216; i += stride) {
    int kk = i >> 15, rem = i & 32767, d = rem >> 8, c = rem & 255;
    wkT[i] = (f16)wkw[(kk << 15) + c * 128 + d];
  }
}

// ---------------------------------------------------------------------------
// Generic 64x64-tile f16 MFMA GEMM: out[m][n] = act(A[m][:] . BT[n][:] + bias[n])
// A: [M][KTOT] (f32 or f16), BT: [N][KTOT] f16.  4 waves, wave = 16 rows x 64 cols.
// ---------------------------------------------------------------------------
template <int KTOT, bool AF32, bool RELU>
__global__ __launch_bounds__(256) void k_gemm64(const void* __restrict__ Aptr,
                                                const f16* __restrict__ BT,
                                                const float* __restrict__ bias,
                                                f16* __restrict__ out, const int NT) {
  __shared__ __align__(16) f16 Al[64][40];  // +8 pad: kills ds_read bank conflicts
  __shared__ __align__(16) f16 Bl[64][40];
  const int m0 = blockIdx.x * 64;
  const int n0 = blockIdx.y * 64;
  const int t = threadIdx.x;
  const int w = t >> 6, l = t & 63, lr = l & 15, lg = l >> 4;
  const int arow = t >> 2, akq = (t & 3) * 8;
  f32x4 acc[4] = {};
  for (int ks = 0; ks < KTOT / 32; ++ks) {
    const int kc = ks * 32;
    __syncthreads();
    if constexpr (AF32) {
      const float* src = (const float*)Aptr + (size_t)(m0 + arow) * KTOT + kc + akq;
      float4 v0 = *(const float4*)src;
      float4 v1 = *(const float4*)(src + 4);
      f16x8 hv = {(f16)v0.x, (f16)v0.y, (f16)v0.z, (f16)v0.w,
                  (f16)v1.x, (f16)v1.y, (f16)v1.z, (f16)v1.w};
      *(f16x8*)&Al[arow][akq] = hv;
    } else {
      const f16* src = (const f16*)Aptr + (size_t)(m0 + arow) * KTOT + kc + akq;
      *(f16x8*)&Al[arow][akq] = *(const f16x8*)src;
    }
    *(f16x8*)&Bl[arow][akq] = *(const f16x8*)(BT + (size_t)(n0 + arow) * KTOT + kc + akq);
    __syncthreads();
    // A-frag: row = lane&15, k = 8*(lane>>4)+j ; B-frag: col = lane&15, same k
    f16x8 af = *(const f16x8*)&Al[16 * w + lr][lg * 8];
#pragma unroll
    for (int nt = 0; nt < 4; ++nt) {
      f16x8 bf = *(const f16x8*)&Bl[nt * 16 + lr][lg * 8];
      acc[nt] = __builtin_amdgcn_mfma_f32_16x16x32_f16(af, bf, acc[nt], 0, 0, 0);
    }
  }
  // C/D: col = lane&15, row = 4*(lane>>4)+r   [m89-verified layout]
#pragma unroll
  for (int nt = 0; nt < 4; ++nt) {
    const int n = n0 + nt * 16 + lr;
    const float bb = bias[n];
#pragma unroll
    for (int r = 0; r < 4; ++r) {
      const int m = m0 + 16 * w + lg * 4 + r;
      float v = acc[nt][r] + bb;
      if (RELU) v = fmaxf(v, 0.f);
      out[(size_t)m * NT + n] = (f16)v;
    }
  }
}

// ---------------------------------------------------------------------------
// K2: z = l2norm(h1 @ w2T + b2). N=128 so each wave owns full rows -> in-wave
// shfl row-norm. Writes z f32 (output) + z f16 (workspace).
// ---------------------------------------------------------------------------
__global__ __launch_bounds__(256) void k_enc2(const f16* __restrict__ A, const f16* __restrict__ BT,
                                              const float* __restrict__ bias,
                                              float* __restrict__ zf32, f16* __restrict__ zf16) {
  __shared__ __align__(16) f16 Al[64][40];
  __shared__ __align__(16) f16 Bl[128][40];
  const int m0 = blockIdx.x * 64;
  const int t = threadIdx.x;
  const int w = t >> 6, l = t & 63, lr = l & 15, lg = l >> 4;
  const int arow = t >> 2, akq = (t & 3) * 8;
  f32x4 acc[8] = {};
  for (int ks = 0; ks < 8; ++ks) {
    const int kc = ks * 32;
    __syncthreads();
    *(f16x8*)&Al[arow][akq] = *(const f16x8*)(A + (size_t)(m0 + arow) * 256 + kc + akq);
#pragma unroll
    for (int hh = 0; hh < 2; ++hh) {
      const int brow = arow + 64 * hh;
      *(f16x8*)&Bl[brow][akq] = *(const f16x8*)(BT + (size_t)brow * 256 + kc + akq);
    }
    __syncthreads();
    f16x8 af = *(const f16x8*)&Al[16 * w + lr][lg * 8];
#pragma unroll
    for (int nt = 0; nt < 8; ++nt) {
      f16x8 bf = *(const f16x8*)&Bl[nt * 16 + lr][lg * 8];
      acc[nt] = __builtin_amdgcn_mfma_f32_16x16x32_f16(af, bf, acc[nt], 0, 0, 0);
    }
  }
  float v[8][4];
#pragma unroll
  for (int nt = 0; nt < 8; ++nt) {
    const float bb = bias[nt * 16 + lr];
#pragma unroll
    for (int r = 0; r < 4; ++r) v[nt][r] = acc[nt][r] + bb;
  }
#pragma unroll
  for (int r = 0; r < 4; ++r) {
    float ss = 0.f;
#pragma unroll
    for (int nt = 0; nt < 8; ++nt) ss += v[nt][r] * v[nt][r];
    ss += __shfl_xor(ss, 1); ss += __shfl_xor(ss, 2); ss += __shfl_xor(ss, 4); ss += __shfl_xor(ss, 8);
    const float scl = 1.f / fmaxf(sqrtf(ss), 1e-12f);
    const int m = m0 + 16 * w + lg * 4 + r;
#pragma unroll
    for (int nt = 0; nt < 8; ++nt) {
      const int n = nt * 16 + lr;
      const float z = v[nt][r] * scl;
      zf32[(size_t)m * 128 + n] = z;
      zf16[(size_t)m * 128 + n] = (f16)z;
    }
  }
}

// ---------------------------------------------------------------------------
// K4: GRU scan. 128 blocks (one batch row each) x 768 threads.
// Thread o: gate g = o>>8 (0=r,1=z,2=n), column c = o&255.
// W_hh row = 128 dwords held as eight 512-bit vectors (VReg_512). A single
// asm statement at the TOP OF EVERY TIMESTEP names all eight as "+v" ->
// all 128 dwords must be simultaneously VGPR-resident each iteration;
// spilling around it would cost 256 scratch ops/step. waves_per_eu(3,3)
// matches runtime occupancy (128 blocks / 256 CUs) -> 170-reg budget.
// h broadcast: wave-uniform ds_read_b128 (16B broadcast, conflict-free).
// ---------------------------------------------------------------------------
__global__ __attribute__((amdgpu_flat_work_group_size(768, 768), amdgpu_waves_per_eu(3, 3)))
void k_gru(const f16* __restrict__ gx, const f16* __restrict__ whh,
           const float* __restrict__ bhh,
           float* __restrict__ cout, f16* __restrict__ cf16) {
  __shared__ __align__(16) f16 h_lds[2][256];
  __shared__ float rz[2][256];
  const int b = blockIdx.x;
  const int o = threadIdx.x;
  const int g = o >> 8;
  const int c = o & 255;
  u32x16 W[8];
  {
    const u32x16* wp = (const u32x16*)(whh + (size_t)o * 256);
#pragma unroll
    for (int i = 0; i < 8; ++i) W[i] = wp[i];
  }
  const float bh = bhh[o];
  if (o < 256) h_lds[0][o] = (f16)0.f;
  float h_own = 0.f;
  const f16* gxp = gx + (size_t)b * 256 * 768 + o;
  float* coutp = cout + (size_t)b * 256 * 256 + c;
  f16* cfp = cf16 + (size_t)b * 256 * 256 + c;
  __syncthreads();
#pragma unroll 1
  for (int tt = 0; tt < 256; ++tt) {
    // --- residency pin: all 128 W dwords must be live in VGPRs HERE, every
    // iteration. Single statement = single program point = no spill window.
    asm volatile("" : "+v"(W[0]), "+v"(W[1]), "+v"(W[2]), "+v"(W[3]),
                      "+v"(W[4]), "+v"(W[5]), "+v"(W[6]), "+v"(W[7]));
    const int cur = tt & 1;
    const float gxv = (float)gxp[tt * 768];
    float a0 = 0.f, a1 = 0.f, a2 = 0.f, a3 = 0.f;
    const uint4* hp = (const uint4*)(&h_lds[cur][0]);
#pragma unroll
    for (int i = 0; i < 32; ++i) {
      const uint4 hv = hp[i];  // wave-uniform address -> LDS broadcast, conflict-free
      const int ch = i >> 2, e = (i & 3) * 4;
      a0 = __builtin_amdgcn_fdot2(u2h(W[ch][e + 0]), u2h(hv.x), a0, false);
      a1 = __builtin_amdgcn_fdot2(u2h(W[ch][e + 1]), u2h(hv.y), a1, false);
      a2 = __builtin_amdgcn_fdot2(u2h(W[ch][e + 2]), u2h(hv.z), a2, false);
      a3 = __builtin_amdgcn_fdot2(u2h(W[ch][e + 3]), u2h(hv.w), a3, false);
    }
    const float dot = (a0 + a1) + (a2 + a3) + bh;  // includes b_hh
    if (g < 2) rz[g][c] = sigm_(gxv + dot);
    __syncthreads();
    if (g == 2) {
      const float r = rz[0][c], zz = rz[1][c];
      const float n = tanh_(gxv + r * dot);
      const float hn = (1.f - zz) * n + zz * h_own;
      h_own = hn;
      h_lds[cur ^ 1][c] = (f16)hn;
      coutp[tt * 256] = hn;
      cfp[tt * 256] = (f16)hn;
    }
    __syncthreads();
  }
}

// ---------------------------------------------------------------------------
// K5: fused preds -> l2norm -> logits -> online LSE / pos / neg-max -> loss&acc.
// grid (tchunk=4, b=128, k=12), 256 threads. Never materializes logits.
// ---------------------------------------------------------------------------
__global__ __launch_bounds__(256) void k_cpc(const f16* __restrict__ cf16, const f16* __restrict__ zf16,
                                             const f16* __restrict__ wkT, const float* __restrict__ wkb,
                                             float* __restrict__ accb) {
  __shared__ __align__(16) f16 SMc[64 * 264];   // c-tile [64][264], reused as z-chunk [64][136]
  __shared__ __align__(16) f16 Bl[128][40];
  __shared__ __align__(16) f16 P[64][136];
  __shared__ float red[2];
  const int tc = blockIdx.x, b = blockIdx.y, kk = blockIdx.z;
  const int t0 = tc * 64;
  const int t = threadIdx.x;
  const int w = t >> 6, l = t & 63, lr = l & 15, lg = l >> 4;
  // ---- stage c tile (64 t-rows x 256 c = 8192 u32, 32 iters of 256) ----
  {
    const uint32_t* src = (const uint32_t*)(cf16 + ((size_t)b * 256 + t0) * 256);
    uint32_t* dst = (uint32_t*)SMc;
#pragma unroll
    for (int it = 0; it < 32; ++it) {
      const int idx = it * 256 + t, row = idx >> 7, cw = idx & 127;
      dst[row * 132 + cw] = src[row * 128 + cw];
    }
  }
  // ---- preds GEMM: (64 x 128) = c(64x256) @ WkT^T, K=256 ----
  f32x4 acc[8] = {};
  for (int ks = 0; ks < 8; ++ks) {
    __syncthreads();
    {
      const uint32_t* bsrc = (const uint32_t*)(wkT + ((size_t)kk << 15));
      uint32_t* bd = (uint32_t*)Bl;
#pragma unroll
      for (int it = 0; it < 8; ++it) {
        const int idx = it * 256 + t, row = idx >> 4, kw = idx & 15;
        bd[row * 20 + kw] = bsrc[row * 128 + ks * 16 + kw];
      }
    }
    __syncthreads();
    f16x8 af = *(const f16x8*)&SMc[(16 * w + lr) * 264 + ks * 32 + lg * 8];
#pragma unroll
    for (int nt = 0; nt < 8; ++nt) {
      f16x8 bf = *(const f16x8*)&Bl[nt * 16 + lr][lg * 8];
      acc[nt] = __builtin_amdgcn_mfma_f32_16x16x32_f16(af, bf, acc[nt], 0, 0, 0);
    }
  }
  // ---- preds epilogue: bias + row l2norm -> P (f16) ----
  {
    float v[8][4];
#pragma unroll
    for (int nt = 0; nt < 8; ++nt) {
      const float bb = wkb[kk * 128 + nt * 16 + lr];
#pragma unroll
      for (int r = 0; r < 4; ++r) v[nt][r] = acc[nt][r] + bb;
    }
#pragma unroll
    for (int r = 0; r < 4; ++r) {
      float ss = 0.f;
#pragma unroll
      for (int nt = 0; nt < 8; ++nt) ss += v[nt][r] * v[nt][r];
      ss += __shfl_xor(ss, 1); ss += __shfl_xor(ss, 2); ss += __shfl_xor(ss, 4); ss += __shfl_xor(ss, 8);
      const float scl = 1.f / fmaxf(sqrtf(ss), 1e-12f);
#pragma unroll
      for (int nt = 0; nt < 8; ++nt)
        P[16 * w + lg * 4 + r][nt * 16 + lr] = (f16)(v[nt][r] * scl);
    }
  }
  __syncthreads();
  // ---- logits + online LSE/pos/negmax over 4 s-chunks of 64 ----
  float m_run[4], s_run[4], pos_v[4], neg_m[4];
#pragma unroll
  for (int r = 0; r < 4; ++r) { m_run[r] = -1e30f; s_run[r] = 0.f; pos_v[r] = -1e30f; neg_m[r] = -1e30f; }
  for (int sc = 0; sc < 4; ++sc) {
    __syncthreads();
    {
      const uint32_t* zsrc = (const uint32_t*)(zf16 + ((size_t)b * 256 + sc * 64) * 128);
      uint32_t* zd = (uint32_t*)SMc;
#pragma unroll
      for (int it = 0; it < 16; ++it) {
        const int idx = it * 256 + t, row = idx >> 6, cw = idx & 63;
        zd[row * 68 + cw] = zsrc[row * 64 + cw];
      }
    }
    __syncthreads();
    f32x4 sa[4] = {};
#pragma unroll
    for (int ks = 0; ks < 4; ++ks) {
      f16x8 af = *(const f16x8*)&P[16 * w + lr][ks * 32 + lg * 8];
#pragma unroll
      for (int nt = 0; nt < 4; ++nt) {
        f16x8 bf = *(const f16x8*)&SMc[(nt * 16 + lr) * 136 + ks * 32 + lg * 8];
        sa[nt] = __builtin_amdgcn_mfma_f32_16x16x32_f16(af, bf, sa[nt], 0, 0, 0);
      }
    }
#pragma unroll
    for (int r = 0; r < 4; ++r) {
      const int trow = t0 + 16 * w + lg * 4 + r;
      const int pos_s = trow + kk + 1;
      float vv[4];
#pragma unroll
      for (int nt = 0; nt < 4; ++nt) vv[nt] = sa[nt][r] * 10.f;  // 1/TEMP
      float cm = fmaxf(fmaxf(vv[0], vv[1]), fmaxf(vv[2], vv[3]));
      cm = fmaxf(cm, __shfl_xor(cm, 1)); cm = fmaxf(cm, __shfl_xor(cm, 2));
      cm = fmaxf(cm, __shfl_xor(cm, 4)); cm = fmaxf(cm, __shfl_xor(cm, 8));
      const float nm = fmaxf(m_run[r], cm);
      float ps = __expf(vv[0] - nm) + __expf(vv[1] - nm) + __expf(vv[2] - nm) + __expf(vv[3] - nm);
      ps += __shfl_xor(ps, 1); ps += __shfl_xor(ps, 2); ps += __shfl_xor(ps, 4); ps += __shfl_xor(ps, 8);
      s_run[r] = s_run[r] * __expf(m_run[r] - nm) + ps;
      m_run[r] = nm;
      const int sbase = sc * 64 + lr;
#pragma unroll
      for (int nt = 0; nt < 4; ++nt) {
        const int s = sbase + nt * 16;
        if (s == pos_s) pos_v[r] = vv[nt];
        else neg_m[r] = fmaxf(neg_m[r], vv[nt]);
      }
    }
  }
  // ---- finalize ----
  __syncthreads();
  if (t == 0) { red[0] = 0.f; red[1] = 0.f; }
  __syncthreads();
  float lsum = 0.f, csum = 0.f;
#pragma unroll
  for (int r = 0; r < 4; ++r) {
    float pv = pos_v[r], ng = neg_m[r];
    pv = fmaxf(pv, __shfl_xor(pv, 1)); pv = fmaxf(pv, __shfl_xor(pv, 2));
    pv = fmaxf(pv, __shfl_xor(pv, 4)); pv = fmaxf(pv, __shfl_xor(pv, 8));
    ng = fmaxf(ng, __shfl_xor(ng, 1)); ng = fmaxf(ng, __shfl_xor(ng, 2));
    ng = fmaxf(ng, __shfl_xor(ng, 4)); ng = fmaxf(ng, __shfl_xor(ng, 8));
    const int trow = t0 + 16 * w + lg * 4 + r;
    if (lr == 0 && trow < 244) {
      const float lse = m_run[r] + __logf(s_run[r]);
      lsum += lse - pv;
      csum += (pv >= ng) ? 1.f : 0.f;
    }
  }
  if (lr == 0) { atomicAdd(&red[0], lsum); atomicAdd(&red[1], csum); }
  __syncthreads();
  if (t == 0) { atomicAdd(&accb[0], red[0]); atomicAdd(&accb[1], red[1]); }
}

__global__ void k_fin(const float* __restrict__ accb, float* __restrict__ out) {
  out[0] = accb[0] * (1.0f / NTOT_LOSS);
  out[1] = accb[1] * (100.0f / NTOT_LOSS);
}

// ---------------------------------------------------------------------------
extern "C" void kernel_launch(void* const* d_in, const int* in_sizes, int n_in,
                              void* d_out, int out_size, void* d_ws, size_t ws_size,
                              hipStream_t stream) {
  (void)in_sizes; (void)n_in; (void)out_size; (void)ws_size;
  const float* rr  = (const float*)d_in[0];
  const float* w1  = (const float*)d_in[1];
  const float* b1  = (const float*)d_in[2];
  const float* w2  = (const float*)d_in[3];
  const float* b2  = (const float*)d_in[4];
  const float* wih = (const float*)d_in[5];
  const float* whh = (const float*)d_in[6];
  const float* bih = (const float*)d_in[7];
  const float* bhh = (const float*)d_in[8];
  const float* wkw = (const float*)d_in[9];
  const float* wkb = (const float*)d_in[10];
  float* out = (float*)d_out;
  char* ws = (char*)d_ws;

  // workspace layout (77.1 MB total)
  const size_t GX_B = (size_t)32768 * 768 * 2;  // 50,331,648
  f16* gx   = (f16*)ws;
  f16* h1   = (f16*)ws;  // alias: h1 (16.8MB) dead before gx is written
  f16* zf16 = (f16*)(ws + GX_B);
  f16* cf16 = (f16*)(ws + GX_B + 8388608);
  f16* w1T  = (f16*)(ws + GX_B + 8388608 + 16777216);
  f16* w2T  = w1T + 65536;
  f16* wihF = w2T + 32768;
  f16* whhF = wihF + 98304;
  f16* wkT  = whhF + 196608;
  float* accb = (float*)(wkT + 393216);

  float* zf32 = out + 2;
  float* cf32 = out + 2 + 4194304;

  k_prep<<<256, 256, 0, stream>>>(w1, w2, wih, whh, wkw, w1T, w2T, wihF, whhF, wkT, accb);
  k_gemm64<256, true, true><<<dim3(512, 4), 256, 0, stream>>>(rr, w1T, b1, h1, 256);
  k_enc2<<<dim3(512), 256, 0, stream>>>(h1, w2T, b2, zf32, zf16);
  k_gemm64<128, false, false><<<dim3(512, 12), 256, 0, stream>>>(zf16, wihF, bih, gx, 768);
  k_gru<<<128, 768, 0, stream>>>(gx, whhF, bhh, cf32, cf16);
  k_cpc<<<dim3(4, 128, 12), 256, 0, stream>>>(cf16, zf16, wkT, wkb, accb);
  k_fin<<<1, 1, 0, stream>>>(accb, out);
}